// Round 10
// baseline (85.813 us; speedup 1.0000x reference)
//
#include <hip/hip_runtime.h>
#include <hip/hip_bf16.h>

// out[8192,64] = L[8192,8192] (fp32) @ M[8192,64] (fp32)
// R10 = R6 geometry (BM=128, 512 thr, 2 blocks/CU) with:
//  - B: direct global->named-VGPR fragment loads from L2-resident BTF
//    (single 32-VGPR set B0..B7, reloaded after MFMA consumption) -> no B LDS.
//  - ZERO barriers: A LDS regions are wave-private; per-wave counted vmcnt(12)
//    (= one step's 4 A-stages + 8 B-loads) orders gl_lds completion vs ds_read.
//  - d_out zeroing folded into build_btf (one less launch, no hipMemsetAsync).
// Split-K=8, fp32 atomics.

#define NPED 8192
#define HID  64
#define BM   128
#define KSPLIT 8
#define KRANGE (NPED / KSPLIT)   // 1024
#define NSTEPS 16                // 64-k steps per k-slice

typedef __bf16 bf16x8 __attribute__((ext_vector_type(8)));
typedef float  f32x4  __attribute__((ext_vector_type(4)));
typedef unsigned short u16;
typedef u16 u16x8 __attribute__((ext_vector_type(8)));

__device__ __forceinline__ bf16x8 cvt8(float4 lo, float4 hi) {
    bf16x8 r;
    r[0] = (__bf16)lo.x; r[1] = (__bf16)lo.y; r[2] = (__bf16)lo.z; r[3] = (__bf16)lo.w;
    r[4] = (__bf16)hi.x; r[5] = (__bf16)hi.y; r[6] = (__bf16)hi.z; r[7] = (__bf16)hi.w;
    return r;
}

__device__ __forceinline__ void gl_lds16(const void* g, void* l) {
    __builtin_amdgcn_global_load_lds(
        (const __attribute__((address_space(1))) void*)g,
        (__attribute__((address_space(3))) void*)l, 16, 0, 0);
}

// ---- K1: zero d_out + build BTF (B [8192,64] fp32 -> fragment-ordered bf16) ----
// BTF[((S*8+f)*64 + l)*8 + j] = bf16(B[S*64 + (f>>2)*32 + (l>>4)*8 + j][(f&3)*16 + (l&15)])
__global__ __launch_bounds__(256)
void build_btf(const float* __restrict__ B, u16* __restrict__ BTF,
               float4* __restrict__ outz) {
    __shared__ u16 t[64][72];
    const int tid = threadIdx.x;
    const int S   = blockIdx.x;          // 0..127
    const int kb  = S * 64;
    {   // zero this block's slice of d_out (131072 float4 total / 128 blocks)
        const float4 z = {0.f, 0.f, 0.f, 0.f};
        #pragma unroll
        for (int i = 0; i < 4; ++i) outz[S * 1024 + i * 256 + tid] = z;
    }
    {
        const int r  = tid >> 2;
        const int c0 = (tid & 3) * 16;
        const float* p = B + (long)(kb + r) * HID + c0;
        #pragma unroll
        for (int j = 0; j < 16; j += 4) {
            float4 v = *(const float4*)(p + j);
            __bf16 b0 = (__bf16)v.x, b1 = (__bf16)v.y, b2 = (__bf16)v.z, b3 = (__bf16)v.w;
            t[c0 + j + 0][r] = __builtin_bit_cast(u16, b0);
            t[c0 + j + 1][r] = __builtin_bit_cast(u16, b1);
            t[c0 + j + 2][r] = __builtin_bit_cast(u16, b2);
            t[c0 + j + 3][r] = __builtin_bit_cast(u16, b3);
        }
    }
    __syncthreads();
    {
        const int f  = tid >> 5;
        const int s  = f >> 2, tt = f & 3;
        const int l0 = (tid & 31) * 2;
        u16* q = BTF + ((long)(S * 8 + f) * 64 + l0) * 8;
        #pragma unroll
        for (int i = 0; i < 2; ++i) {
            const int l  = l0 + i;
            const int h  = tt * 16 + (l & 15);
            const int kl = s * 32 + (l >> 4) * 8;
            u16x8 v;
            #pragma unroll
            for (int j = 0; j < 8; ++j) v[j] = t[h][kl + j];
            *(u16x8*)(q + i * 8) = v;
        }
    }
}

// ---- K2: barrier-free streaming MFMA ----
__global__ __launch_bounds__(512, 4)
void crowd_mm(const float* __restrict__ A, const u16* __restrict__ BTF,
              float* __restrict__ out)
{
    __shared__ float Aa[BM * 64];   // 32 KB, wave-private 1/8ths, XOR-swizzled
    __shared__ float Ab[BM * 64];   // 32 KB

    const int tid  = threadIdx.x;
    const int lane = tid & 63;
    const int w    = tid >> 6;       // wave 0..7, owns rows w*16..+15
    const int rb   = blockIdx.x;     // 0..63
    const int ks   = blockIdx.y;     // 0..7

    const int l15  = lane & 15;
    const int l4   = lane >> 4;
    const int cb16 = l15 * 16;

    const char* Abase = (const char*)(A + (long)(rb * BM) * NPED + (long)ks * KRANGE);
    const u16*  Bp    = BTF + (long)(ks * NSTEPS) * 4096 + lane * 8;

    u16x8 B0, B1, B2, B3, B4, B5, B6, B7;   // single named set, 32 VGPR
    f32x4 acc[4] = {};

    // A stage for step STEP: 4 gl_lds/wave, wave-private rows w*16..+15.
    // LDS[row][x] = A[row][x ^ ((row&7)<<4)] (pre-swizzled source col).
#define STAGE_A(LBUF, STEP) do {                                                 \
    _Pragma("unroll")                                                            \
    for (int I = 0; I < 4; ++I) {                                                \
        const int row4 = w * 16 + I * 4 + l4;                                    \
        const char* src = Abase + (long)row4 * (NPED * 4)                        \
                        + (STEP) * 256 + (cb16 ^ ((row4 & 7) << 4));             \
        gl_lds16(src, (char*)(LBUF) + (w * 4 + I) * 1024);                       \
    }                                                                            \
} while (0)

#define LOADB(STEP) do {                                                         \
    const u16* bp_ = Bp + (STEP) * 4096;                                         \
    B0 = *(const u16x8*)(bp_ + 0 * 512);                                         \
    B1 = *(const u16x8*)(bp_ + 1 * 512);                                         \
    B2 = *(const u16x8*)(bp_ + 2 * 512);                                         \
    B3 = *(const u16x8*)(bp_ + 3 * 512);                                         \
    B4 = *(const u16x8*)(bp_ + 4 * 512);                                         \
    B5 = *(const u16x8*)(bp_ + 5 * 512);                                         \
    B6 = *(const u16x8*)(bp_ + 6 * 512);                                         \
    B7 = *(const u16x8*)(bp_ + 7 * 512);                                         \
} while (0)

    // Per-wave step, NO barriers. vmcnt(VM) guarantees A(S)'s gl_lds landed
    // (12 = 4 A(S+1) + 8 B(S) allowed in flight). Compiler's own vmcnt for the
    // B-reg MFMA dependency handles B(S). LOADB(S+1) sits AFTER the MFMAs
    // (sched_barrier-pinned) so one 32-VGPR B set suffices.
#define STEPM(S, VM) do {                                                        \
    asm volatile("s_waitcnt vmcnt(" #VM ")" ::: "memory");                       \
    __builtin_amdgcn_sched_barrier(0);                                           \
    const char* ab_ = ((S) & 1) ? (const char*)Ab : (const char*)Aa;             \
    const int row_ = w * 16 + l15;                                               \
    const int sw_  = (row_ & 7) << 4;                                            \
    const int rB_  = row_ * 256;                                                 \
    float4 fa0 = *(const float4*)(ab_ + rB_ + ((l4 * 32)            ^ sw_));     \
    float4 fa1 = *(const float4*)(ab_ + rB_ + ((l4 * 32 + 16)       ^ sw_));     \
    float4 fa2 = *(const float4*)(ab_ + rB_ + ((128 + l4 * 32)      ^ sw_));     \
    float4 fa3 = *(const float4*)(ab_ + rB_ + ((128 + l4 * 32 + 16) ^ sw_));     \
    asm volatile("s_waitcnt lgkmcnt(0)" ::: "memory");                           \
    __builtin_amdgcn_sched_barrier(0);                                           \
    if ((S) + 2 < NSTEPS) {                                                      \
        if ((S) & 1) STAGE_A(Ab, (S) + 2); else STAGE_A(Aa, (S) + 2);            \
    }                                                                            \
    bf16x8 af0 = cvt8(fa0, fa1);                                                 \
    bf16x8 af1 = cvt8(fa2, fa3);                                                 \
    acc[0] = __builtin_amdgcn_mfma_f32_16x16x32_bf16(                            \
        af0, __builtin_bit_cast(bf16x8, B0), acc[0], 0, 0, 0);                   \
    acc[1] = __builtin_amdgcn_mfma_f32_16x16x32_bf16(                            \
        af0, __builtin_bit_cast(bf16x8, B1), acc[1], 0, 0, 0);                   \
    acc[2] = __builtin_amdgcn_mfma_f32_16x16x32_bf16(                            \
        af0, __builtin_bit_cast(bf16x8, B2), acc[2], 0, 0, 0);                   \
    acc[3] = __builtin_amdgcn_mfma_f32_16x16x32_bf16(                            \
        af0, __builtin_bit_cast(bf16x8, B3), acc[3], 0, 0, 0);                   \
    acc[0] = __builtin_amdgcn_mfma_f32_16x16x32_bf16(                            \
        af1, __builtin_bit_cast(bf16x8, B4), acc[0], 0, 0, 0);                   \
    acc[1] = __builtin_amdgcn_mfma_f32_16x16x32_bf16(                            \
        af1, __builtin_bit_cast(bf16x8, B5), acc[1], 0, 0, 0);                   \
    acc[2] = __builtin_amdgcn_mfma_f32_16x16x32_bf16(                            \
        af1, __builtin_bit_cast(bf16x8, B6), acc[2], 0, 0, 0);                   \
    acc[3] = __builtin_amdgcn_mfma_f32_16x16x32_bf16(                            \
        af1, __builtin_bit_cast(bf16x8, B7), acc[3], 0, 0, 0);                   \
    __builtin_amdgcn_sched_barrier(0);                                           \
    if ((S) + 1 < NSTEPS) LOADB((S) + 1);                                        \
} while (0)

    // Prologue: A(0), A(1) staged; B(0) in regs. Entry queue at step 0:
    // [A0x4, A1x4, B0x8] = 16 -> vmcnt(12) drains A0.
    STAGE_A(Aa, 0);
    STAGE_A(Ab, 1);
    LOADB(0);

    STEPM(0, 12);  STEPM(1, 12);  STEPM(2, 12);  STEPM(3, 12);
    STEPM(4, 12);  STEPM(5, 12);  STEPM(6, 12);  STEPM(7, 12);
    STEPM(8, 12);  STEPM(9, 12);  STEPM(10, 12); STEPM(11, 12);
    STEPM(12, 12); STEPM(13, 12); STEPM(14, 12); STEPM(15, 8);

    // Epilogue: C/D layout col = lane&15, row = (lane>>4)*4 + reg
    #pragma unroll
    for (int t = 0; t < 4; ++t) {
        #pragma unroll
        for (int r = 0; r < 4; ++r) {
            int row = rb * BM + w * 16 + l4 * 4 + r;
            int col = t * 16 + l15;
            atomicAdd(&out[row * HID + col], acc[t][r]);
        }
    }
#undef STAGE_A
#undef LOADB
#undef STEPM
}

extern "C" void kernel_launch(void* const* d_in, const int* in_sizes, int n_in,
                              void* d_out, int out_size, void* d_ws, size_t ws_size,
                              hipStream_t stream) {
    const float* A = (const float*)d_in[0];   // location_data [8192, 8192]
    const float* B = (const float*)d_in[1];   // motion_data   [8192, 64]
    float* out = (float*)d_out;               // [8192, 64]
    u16* BTF = (u16*)d_ws;                    // 1 MB fragment-ordered B

    build_btf<<<dim3(NPED / 64), 256, 0, stream>>>(B, BTF, (float4*)d_out);

    dim3 grid(NPED / BM, KSPLIT);
    crowd_mm<<<grid, 512, 0, stream>>>(A, BTF, out);
}